// Round 1
// baseline (574.753 us; speedup 1.0000x reference)
//
#include <hip/hip_runtime.h>
#include <hip/hip_bf16.h>

// Problem: out[b,s,o] = x @ w_eff^T + bias, where
//   w_eff[o][k] = r*lut4[o][c4] + (1-r)*lut5[o][2*c4+b4]
//   c4 from bitplanes 0..3 (plane0 = MSB), b4 = plane 4, bit k%32 of int32 k/32
//   r = 2 - 3*sigmoid(z)
// M=8192, N=4096, K=4096.

#define IN_F   4096
#define OUT_F  4096
#define M_DIM  8192   // 4*2048

typedef __bf16          bf16x8   __attribute__((ext_vector_type(8)));
typedef float           f32x4    __attribute__((ext_vector_type(4)));
typedef unsigned short  ushortx8 __attribute__((ext_vector_type(8)));

__device__ __forceinline__ unsigned short f32_to_bf16(float f) {
    unsigned int u = __builtin_bit_cast(unsigned int, f);
    u += 0x7fffu + ((u >> 16) & 1u);   // round-to-nearest-even (finite values only here)
    return (unsigned short)(u >> 16);
}

__device__ __forceinline__ void async_load16(const void* g, void* l) {
    __builtin_amdgcn_global_load_lds(
        (const __attribute__((address_space(1))) unsigned int*)g,
        (__attribute__((address_space(3))) unsigned int*)l,
        16, 0, 0);
}

// ---------------------------------------------------------------------------
// Kernel 1: bitplane LUT dequant -> bf16 w_eff [OUT_F][IN_F]
// One thread per packed int32 group (32 weights). 256 threads/block = 2 rows.
// ---------------------------------------------------------------------------
__global__ __launch_bounds__(256) void dequant_kernel(
    const unsigned int* __restrict__ qw,   // [6][OUT_F][IN_F/32]
    const float* __restrict__ lut4,        // [OUT_F][16]
    const float* __restrict__ lut5,        // [OUT_F][32]
    const float* __restrict__ zp,          // scalar
    unsigned short* __restrict__ W)        // bf16 [OUT_F][IN_F]
{
    __shared__ float s4[2][16];
    __shared__ float s5[2][32];
    const int tid = threadIdx.x;
    const int o0 = blockIdx.x * 2;
    if (tid < 32) {
        s4[tid >> 4][tid & 15] = lut4[o0 * 16 + tid];
    } else if (tid < 96) {
        const int t = tid - 32;
        s5[t >> 5][t & 31] = lut5[o0 * 32 + t];
    }
    __syncthreads();

    const int gid = blockIdx.x * 256 + tid;   // group id, 0 .. OUT_F*IN_F/32-1
    const int o   = gid >> 7;                 // /(IN_F/32)
    const int lo  = o & 1;

    const float z   = zp[0];
    const float sig = 1.0f / (1.0f + __expf(-z));
    const float r   = 2.0f - 3.0f * sig;      // r = 1 - (p - 4), p = 3*sig + 3
    const float ri  = 1.0f - r;

    const int PS = OUT_F * (IN_F / 32);
    const unsigned int q0 = qw[0 * PS + gid];
    const unsigned int q1 = qw[1 * PS + gid];
    const unsigned int q2 = qw[2 * PS + gid];
    const unsigned int q3 = qw[3 * PS + gid];
    const unsigned int q4 = qw[4 * PS + gid];

    unsigned short outv[32];
    #pragma unroll
    for (int i = 0; i < 32; ++i) {
        const unsigned c4 = (((q0 >> i) & 1u) << 3) | (((q1 >> i) & 1u) << 2) |
                            (((q2 >> i) & 1u) << 1) |  ((q3 >> i) & 1u);
        const unsigned c5 = (c4 << 1) | ((q4 >> i) & 1u);
        const float w = r * s4[lo][c4] + ri * s5[lo][c5];
        outv[i] = f32_to_bf16(w);
    }

    ushortx8* dst = (ushortx8*)(W + (size_t)gid * 32);   // 64B contiguous per thread
    #pragma unroll
    for (int j = 0; j < 4; ++j) {
        ushortx8 v;
        #pragma unroll
        for (int e = 0; e < 8; ++e) v[e] = outv[j * 8 + e];
        dst[j] = v;
    }
}

// ---------------------------------------------------------------------------
// Kernel 2: x fp32 -> bf16 cast (memory-bound)
// ---------------------------------------------------------------------------
__global__ __launch_bounds__(256) void cast_bf16_kernel(
    const float* __restrict__ x, unsigned short* __restrict__ xb)
{
    const size_t i = ((size_t)blockIdx.x * 256 + threadIdx.x) * 8;
    const f32x4 a = *(const f32x4*)(x + i);
    const f32x4 b = *(const f32x4*)(x + i + 4);
    ushortx8 o;
    #pragma unroll
    for (int e = 0; e < 4; ++e) o[e]     = f32_to_bf16(a[e]);
    #pragma unroll
    for (int e = 0; e < 4; ++e) o[4 + e] = f32_to_bf16(b[e]);
    *(ushortx8*)(xb + i) = o;
}

// ---------------------------------------------------------------------------
// Kernel 3: bf16 GEMM, C[M][N] = A[M][K] * B[N][K]^T + bias, fp32 out.
// m97-style: 128x128 tile, BK=32, 4 waves x (64x64), global_load_lds width 16.
// ---------------------------------------------------------------------------
__global__ __launch_bounds__(256) void gemm_bt_kernel(
    const unsigned short* __restrict__ A,   // bf16 [M_DIM][IN_F]
    const unsigned short* __restrict__ B,   // bf16 [OUT_F][IN_F]
    const float* __restrict__ bias,         // [OUT_F]
    float* __restrict__ C)                  // [M_DIM][OUT_F]
{
    __shared__ unsigned short sA[128 * 32]; // 8 KB, contiguous row-major (no pad: global_load_lds)
    __shared__ unsigned short sB[128 * 32]; // 8 KB

    const int tid  = threadIdx.x;
    const int lane = tid & 63;
    const int wave = tid >> 6;
    const int bn = blockIdx.x;              // N tile 0..31
    const int bm = blockIdx.y;              // M tile 0..63

    const int wm  = (wave & 1) << 6;        // wave quadrant: 64x64
    const int wn  = (wave >> 1) << 6;
    const int l15 = lane & 15;
    const int q   = lane >> 4;

    // Staging: pass0 = elements [tid*8, tid*8+8) of the 128x32 tile, pass1 = +2048.
    // LDS dest offset = tid*16 bytes -> wave-uniform base + lane*16 (global_load_lds semantics).
    const int e0 = tid * 8;
    const int r0 = e0 >> 5;
    const int c0 = e0 & 31;

    const unsigned short* gA0 = A + (size_t)(bm * 128 + r0) * IN_F + c0;
    const unsigned short* gA1 = gA0 + (size_t)64 * IN_F;
    const unsigned short* gB0 = B + (size_t)(bn * 128 + r0) * IN_F + c0;
    const unsigned short* gB1 = gB0 + (size_t)64 * IN_F;
    char* lA0 = (char*)sA + e0 * 2;
    char* lA1 = lA0 + 4096;
    char* lB0 = (char*)sB + e0 * 2;
    char* lB1 = lB0 + 4096;

    f32x4 acc[4][4] = {};

    // Fragment LDS element offsets: A[m=l15][k=q*8+j] pattern, row stride 32.
    const int aoff = (wm + l15) * 32 + q * 8;
    const int boff = (wn + l15) * 32 + q * 8;

    for (int k0 = 0; k0 < IN_F; k0 += 32) {
        async_load16(gA0 + k0, lA0);
        async_load16(gA1 + k0, lA1);
        async_load16(gB0 + k0, lB0);
        async_load16(gB1 + k0, lB1);
        __syncthreads();   // drains vmcnt (global_load_lds) + barrier

        bf16x8 af[4], bf[4];
        #pragma unroll
        for (int mi = 0; mi < 4; ++mi)
            af[mi] = *(const bf16x8*)(sA + aoff + mi * 512);   // ds_read_b128
        #pragma unroll
        for (int ni = 0; ni < 4; ++ni)
            bf[ni] = *(const bf16x8*)(sB + boff + ni * 512);

        #pragma unroll
        for (int mi = 0; mi < 4; ++mi)
            #pragma unroll
            for (int ni = 0; ni < 4; ++ni)
                acc[mi][ni] = __builtin_amdgcn_mfma_f32_16x16x32_bf16(
                    af[mi], bf[ni], acc[mi][ni], 0, 0, 0);

        __syncthreads();   // protect LDS from next iteration's staging
    }

    // Epilogue: C/D layout col = lane&15, row = (lane>>4)*4 + reg  [m89-verified]
    const int col0 = bn * 128 + wn + l15;
    const int row0 = bm * 128 + wm + q * 4;
    #pragma unroll
    for (int ni = 0; ni < 4; ++ni) {
        const int col = col0 + ni * 16;
        const float bv = bias[col];
        #pragma unroll
        for (int mi = 0; mi < 4; ++mi) {
            const int row = row0 + mi * 16;
            #pragma unroll
            for (int r = 0; r < 4; ++r)
                C[(size_t)(row + r) * OUT_F + col] = acc[mi][ni][r] + bv;
        }
    }
}

extern "C" void kernel_launch(void* const* d_in, const int* in_sizes, int n_in,
                              void* d_out, int out_size, void* d_ws, size_t ws_size,
                              hipStream_t stream)
{
    const float*        x    = (const float*)d_in[0];        // (4,2048,4096)
    const float*        z    = (const float*)d_in[1];        // scalar
    const float*        lut4 = (const float*)d_in[2];        // (4096,16)
    const float*        lut5 = (const float*)d_in[3];        // (4096,32)
    const float*        bias = (const float*)d_in[4];        // (4096,)
    const unsigned int* qw   = (const unsigned int*)d_in[5]; // (6,4096,128)
    float* out = (float*)d_out;                              // (4,2048,4096)

    // Workspace: xb (bf16, 64 MB) then wb (bf16, 32 MB)
    unsigned short* xb = (unsigned short*)d_ws;
    unsigned short* wb = xb + (size_t)M_DIM * IN_F;

    dequant_kernel<<<OUT_F * (IN_F / 32) / 256, 256, 0, stream>>>(qw, lut4, lut5, z, wb);
    cast_bf16_kernel<<<(M_DIM * (size_t)IN_F) / (8 * 256), 256, 0, stream>>>(x, xb);
    gemm_bt_kernel<<<dim3(OUT_F / 128, M_DIM / 128), 256, 0, stream>>>(xb, wb, bias, out);
}

// Round 2
// 571.260 us; speedup vs baseline: 1.0061x; 1.0061x over previous
//
#include <hip/hip_runtime.h>
#include <hip/hip_bf16.h>

// out[b,s,o] = x @ w_eff^T + bias, where
//   w_eff[o][k] = r*lut4[o][c4] + (1-r)*lut5[o][c5],  c5 = 2*c4 + b4
//   combined: lut_c[o][c5] = r*lut4[o][c5>>1] + (1-r)*lut5[o][c5]  (one lookup)
//   r = 2 - 3*sigmoid(z).  M=8192, N=4096, K=4096.

#define IN_F   4096
#define OUT_F  4096
#define M_DIM  8192   // 4*2048

#define CAST_BLOCKS 8192   // M*K/(16*256)
#define DEQ_BLOCKS  2048   // OUT_F*(IN_F/32)/256

typedef __bf16          bf16x8   __attribute__((ext_vector_type(8)));
typedef float           f32x4    __attribute__((ext_vector_type(4)));
typedef unsigned short  ushortx8 __attribute__((ext_vector_type(8)));

__device__ __forceinline__ unsigned short f32_to_bf16(float f) {
    unsigned int u = __builtin_bit_cast(unsigned int, f);
    u += 0x7fffu + ((u >> 16) & 1u);   // RNE (finite values only here)
    return (unsigned short)(u >> 16);
}

__device__ __forceinline__ void async_load16(const void* g, void* l) {
    __builtin_amdgcn_global_load_lds(
        (const __attribute__((address_space(1))) unsigned int*)g,
        (__attribute__((address_space(3))) unsigned int*)l,
        16, 0, 0);
}

// ---------------------------------------------------------------------------
// Kernel 1 (fused prologue): blocks [0,CAST_BLOCKS) cast x fp32->bf16,
// blocks [CAST_BLOCKS, CAST_BLOCKS+DEQ_BLOCKS) dequant weights via combined LUT.
// Both memory-bound; fusing overlaps them and removes one launch/drain gap.
// ---------------------------------------------------------------------------
__global__ __launch_bounds__(256) void prologue_kernel(
    const float* __restrict__ x,           // [M_DIM][IN_F] fp32
    const unsigned int* __restrict__ qw,   // [6][OUT_F][IN_F/32]
    const float* __restrict__ lut4,        // [OUT_F][16]
    const float* __restrict__ lut5,        // [OUT_F][32]
    const float* __restrict__ zp,          // scalar
    unsigned short* __restrict__ xb,       // bf16 [M_DIM][IN_F]
    unsigned short* __restrict__ W)        // bf16 [OUT_F][IN_F]
{
    const int tid = threadIdx.x;

    if (blockIdx.x < CAST_BLOCKS) {
        // ---- cast: 16 elements per thread ----
        const size_t i = (size_t)blockIdx.x * 4096 + (size_t)tid * 16;
        const f32x4* src = (const f32x4*)(x + i);
        f32x4 a0 = src[0], a1 = src[1], a2 = src[2], a3 = src[3];
        ushortx8 o0, o1;
        #pragma unroll
        for (int e = 0; e < 4; ++e) {
            o0[e]     = f32_to_bf16(a0[e]);
            o0[4 + e] = f32_to_bf16(a1[e]);
            o1[e]     = f32_to_bf16(a2[e]);
            o1[4 + e] = f32_to_bf16(a3[e]);
        }
        ushortx8* dst = (ushortx8*)(xb + i);
        dst[0] = o0;
        dst[1] = o1;
        return;
    }

    // ---- dequant: one thread per packed int32 (32 weights), 2 rows/block ----
    __shared__ float sc[2][32];            // combined LUT, fp32 (32 banks/row)
    const int bid = blockIdx.x - CAST_BLOCKS;
    const int o0 = bid * 2;

    if (tid < 64) {
        const float z   = zp[0];
        const float sig = 1.0f / (1.0f + __expf(-z));
        const float r   = 2.0f - 3.0f * sig;   // r = 1 - (p - 4), p = 3*sig + 3
        const float ri  = 1.0f - r;
        const int row = tid >> 5;
        const int c   = tid & 31;
        sc[row][c] = r * lut4[(o0 + row) * 16 + (c >> 1)]
                   + ri * lut5[(o0 + row) * 32 + c];
    }
    __syncthreads();

    const int gid = bid * 256 + tid;       // group id, 0 .. OUT_F*IN_F/32-1
    const int lo  = (gid >> 7) & 1;        // row within block

    const int PS = OUT_F * (IN_F / 32);
    const unsigned int q0 = qw[0 * PS + gid];
    const unsigned int q1 = qw[1 * PS + gid];
    const unsigned int q2 = qw[2 * PS + gid];
    const unsigned int q3 = qw[3 * PS + gid];
    const unsigned int q4 = qw[4 * PS + gid];

    unsigned short outv[32];
    #pragma unroll
    for (int i = 0; i < 32; ++i) {
        const unsigned c5 = (((q0 >> i) & 1u) << 4) | (((q1 >> i) & 1u) << 3) |
                            (((q2 >> i) & 1u) << 2) | (((q3 >> i) & 1u) << 1) |
                             ((q4 >> i) & 1u);
        outv[i] = f32_to_bf16(sc[lo][c5]);
    }

    ushortx8* dst = (ushortx8*)(W + (size_t)gid * 32);   // 64B contiguous/thread
    #pragma unroll
    for (int j = 0; j < 4; ++j) {
        ushortx8 v;
        #pragma unroll
        for (int e = 0; e < 8; ++e) v[e] = outv[j * 8 + e];
        dst[j] = v;
    }
}

// ---------------------------------------------------------------------------
// Kernel 2: bf16 GEMM, C[M][N] = A[M][K] * B[N][K]^T + bias, fp32 out.
// m97-style: 128x128 tile, BK=32, 4 waves x (64x64), global_load_lds width 16.
// ---------------------------------------------------------------------------
__global__ __launch_bounds__(256) void gemm_bt_kernel(
    const unsigned short* __restrict__ A,   // bf16 [M_DIM][IN_F]
    const unsigned short* __restrict__ B,   // bf16 [OUT_F][IN_F]
    const float* __restrict__ bias,         // [OUT_F]
    float* __restrict__ C)                  // [M_DIM][OUT_F]
{
    __shared__ unsigned short sA[128 * 32]; // 8 KB, contiguous (global_load_lds)
    __shared__ unsigned short sB[128 * 32]; // 8 KB

    const int tid  = threadIdx.x;
    const int lane = tid & 63;
    const int wave = tid >> 6;
    const int bn = blockIdx.x;              // N tile 0..31
    const int bm = blockIdx.y;              // M tile 0..63

    const int wm  = (wave & 1) << 6;        // wave quadrant: 64x64
    const int wn  = (wave >> 1) << 6;
    const int l15 = lane & 15;
    const int q   = lane >> 4;

    const int e0 = tid * 8;
    const int r0 = e0 >> 5;
    const int c0 = e0 & 31;

    const unsigned short* gA0 = A + (size_t)(bm * 128 + r0) * IN_F + c0;
    const unsigned short* gA1 = gA0 + (size_t)64 * IN_F;
    const unsigned short* gB0 = B + (size_t)(bn * 128 + r0) * IN_F + c0;
    const unsigned short* gB1 = gB0 + (size_t)64 * IN_F;
    char* lA0 = (char*)sA + e0 * 2;
    char* lA1 = lA0 + 4096;
    char* lB0 = (char*)sB + e0 * 2;
    char* lB1 = lB0 + 4096;

    f32x4 acc[4][4] = {};

    const int aoff = (wm + l15) * 32 + q * 8;
    const int boff = (wn + l15) * 32 + q * 8;

    for (int k0 = 0; k0 < IN_F; k0 += 32) {
        async_load16(gA0 + k0, lA0);
        async_load16(gA1 + k0, lA1);
        async_load16(gB0 + k0, lB0);
        async_load16(gB1 + k0, lB1);
        __syncthreads();   // drains vmcnt (global_load_lds) + barrier

        bf16x8 af[4], bf[4];
        #pragma unroll
        for (int mi = 0; mi < 4; ++mi)
            af[mi] = *(const bf16x8*)(sA + aoff + mi * 512);   // ds_read_b128
        #pragma unroll
        for (int ni = 0; ni < 4; ++ni)
            bf[ni] = *(const bf16x8*)(sB + boff + ni * 512);

        #pragma unroll
        for (int mi = 0; mi < 4; ++mi)
            #pragma unroll
            for (int ni = 0; ni < 4; ++ni)
                acc[mi][ni] = __builtin_amdgcn_mfma_f32_16x16x32_bf16(
                    af[mi], bf[ni], acc[mi][ni], 0, 0, 0);

        __syncthreads();
    }

    // Epilogue: C/D layout col = lane&15, row = (lane>>4)*4 + reg  [m89-verified]
    const int col0 = bn * 128 + wn + l15;
    const int row0 = bm * 128 + wm + q * 4;
    #pragma unroll
    for (int ni = 0; ni < 4; ++ni) {
        const int col = col0 + ni * 16;
        const float bv = bias[col];
        #pragma unroll
        for (int mi = 0; mi < 4; ++mi) {
            const int row = row0 + mi * 16;
            #pragma unroll
            for (int r = 0; r < 4; ++r)
                C[(size_t)(row + r) * OUT_F + col] = acc[mi][ni][r] + bv;
        }
    }
}

extern "C" void kernel_launch(void* const* d_in, const int* in_sizes, int n_in,
                              void* d_out, int out_size, void* d_ws, size_t ws_size,
                              hipStream_t stream)
{
    const float*        x    = (const float*)d_in[0];        // (4,2048,4096)
    const float*        z    = (const float*)d_in[1];        // scalar
    const float*        lut4 = (const float*)d_in[2];        // (4096,16)
    const float*        lut5 = (const float*)d_in[3];        // (4096,32)
    const float*        bias = (const float*)d_in[4];        // (4096,)
    const unsigned int* qw   = (const unsigned int*)d_in[5]; // (6,4096,128)
    float* out = (float*)d_out;                              // (4,2048,4096)

    unsigned short* xb = (unsigned short*)d_ws;              // bf16, 64 MB
    unsigned short* wb = xb + (size_t)M_DIM * IN_F;          // bf16, 32 MB

    prologue_kernel<<<CAST_BLOCKS + DEQ_BLOCKS, 256, 0, stream>>>(
        x, qw, lut4, lut5, z, xb, wb);
    gemm_bt_kernel<<<dim3(OUT_F / 128, M_DIM / 128), 256, 0, stream>>>(xb, wb, bias, out);
}